// Round 6
// baseline (293.276 us; speedup 1.0000x reference)
//
#include <hip/hip_runtime.h>
#include <hip/hip_bf16.h>

#define N_NODES 50000
#define PADN    50048   // 391 * 128
#define N_EDGES 800000
#define N_RELS  8
#define NB_SCAN 196     // ceil(50000/256)

typedef __attribute__((ext_vector_type(8))) short bf16x8;
typedef __attribute__((ext_vector_type(4))) float f32x4;

__device__ __forceinline__ unsigned short f2b(float f) {
    unsigned int u = __float_as_uint(f);
    u += 0x7fffu + ((u >> 16) & 1u);
    return (unsigned short)(u >> 16);
}

// ---- convert h (fp32 -> bf16), 4 elems/thread ----
__global__ void cvt_h_kernel(const float* __restrict__ h, unsigned short* __restrict__ hb) {
    int i = blockIdx.x * 256 + threadIdx.x;          // 1,600,000 float4 chunks
    float4 v = ((const float4*)h)[i];
    ushort4 o;
    o.x = f2b(v.x); o.y = f2b(v.y); o.z = f2b(v.z); o.w = f2b(v.w);
    ((ushort4*)hb)[i] = o;
}

// ---- convert W to MFMA-fragment layout: wt2[r][o>>4][k>>3][o&15][k&7] bf16 ----
// A-fragment for (r, o-group go, chunk c): 256 B contiguous, lane m16 reads 16 B.
__global__ void cvt_w_kernel(const float* __restrict__ w, unsigned short* __restrict__ wt2) {
    int idx = blockIdx.x * 256 + threadIdx.x;        // 131072 = 8*128*128
    int r = idx >> 14;
    int k = (idx >> 7) & 127;
    int o = idx & 127;
    int off = (r << 14) + ((o >> 4) << 11) + ((k >> 3) << 7) + ((o & 15) << 3) + (k & 7);
    wt2[off] = f2b(w[idx]);
}

// ---- histogram of dst ----
__global__ void hist_kernel(const int* __restrict__ dst, int* __restrict__ counts) {
    int e = blockIdx.x * 256 + threadIdx.x;
    atomicAdd(&counts[dst[e]], 1);
}

// ---- scan phase 1 ----
__global__ void scan1_kernel(const int* __restrict__ counts, int* __restrict__ partial,
                             int* __restrict__ bsum) {
    __shared__ int tmp[256];
    int i = blockIdx.x * 256 + threadIdx.x;
    int v = (i < N_NODES) ? counts[i] : 0;
    tmp[threadIdx.x] = v;
    __syncthreads();
    #pragma unroll
    for (int off = 1; off < 256; off <<= 1) {
        int t = (threadIdx.x >= off) ? tmp[threadIdx.x - off] : 0;
        __syncthreads();
        tmp[threadIdx.x] += t;
        __syncthreads();
    }
    if (i < N_NODES) partial[i] = tmp[threadIdx.x] - v;
    if (threadIdx.x == 255) bsum[blockIdx.x] = tmp[255];
}

// ---- scan phase 2 ----
__global__ void scan2_kernel(int* __restrict__ bsum) {
    __shared__ int tmp[256];
    int i = threadIdx.x;
    int v = (i < NB_SCAN) ? bsum[i] : 0;
    tmp[i] = v;
    __syncthreads();
    #pragma unroll
    for (int off = 1; off < 256; off <<= 1) {
        int t = (i >= off) ? tmp[i - off] : 0;
        __syncthreads();
        tmp[i] += t;
        __syncthreads();
    }
    if (i < NB_SCAN) bsum[i] = tmp[i] - v;
}

// ---- scan phase 3 ----
__global__ void scan3_kernel(const int* __restrict__ partial, const int* __restrict__ bsum,
                             int* __restrict__ row_start, int* __restrict__ cursor) {
    int i = blockIdx.x * 256 + threadIdx.x;
    if (i < N_NODES) {
        int rs = partial[i] + bsum[i >> 8];
        row_start[i] = rs;
        cursor[i] = rs;
    }
    if (i == 0) row_start[N_NODES] = N_EDGES;
}

// ---- scatter: meta.x = (src << 8) | et  (hb bf16 row byte offset | rel) ----
__global__ void scatter_kernel(const int* __restrict__ src, const int* __restrict__ dst,
                               const int* __restrict__ et, const float* __restrict__ en,
                               int* __restrict__ cursor, int2* __restrict__ meta) {
    int e = blockIdx.x * 256 + threadIdx.x;
    int d = dst[e];
    int pos = atomicAdd(&cursor[d], 1);
    meta[pos] = make_int2((src[e] << 8) | et[e], __float_as_int(en[e]));
}

// ---- aggregate: one wave per dst node; per-rel fp32 accumulate of norm*hb[src];
//      writes agg[r][node][128] bf16 (rel-major planes, PADN rows each) ----
__global__ __launch_bounds__(256) void agg_kernel(const char* __restrict__ hb,
                                                  const int2* __restrict__ meta,
                                                  const int* __restrict__ row_start,
                                                  unsigned short* __restrict__ agg) {
    int node = blockIdx.x * 4 + (threadIdx.x >> 6);   // 12500 * 4 = 50000
    int lane = threadIdx.x & 63;
    int beg = row_start[node], end = row_start[node + 1];
    float2 acc[N_RELS];
    #pragma unroll
    for (int r = 0; r < N_RELS; ++r) acc[r] = make_float2(0.f, 0.f);

    for (int base = beg; base < end; base += 64) {
        int cnt = end - base; if (cnt > 64) cnt = 64;
        int2 m = make_int2(0, 0);
        if (base + lane < end) m = meta[base + lane];
        #pragma unroll 4
        for (int k = 0; k < cnt; ++k) {
            int off = __shfl(m.x, k);
            float w = __uint_as_float(__shfl(m.y, k));
            unsigned int v = *(const unsigned int*)(hb + (off & 0xFFFFFF00) + lane * 4);
            int r = __builtin_amdgcn_readfirstlane(off) & 7;
            float vx = __uint_as_float(v << 16) * w;
            float vy = __uint_as_float(v & 0xffff0000u) * w;
            switch (r) {
                case 0: acc[0].x += vx; acc[0].y += vy; break;
                case 1: acc[1].x += vx; acc[1].y += vy; break;
                case 2: acc[2].x += vx; acc[2].y += vy; break;
                case 3: acc[3].x += vx; acc[3].y += vy; break;
                case 4: acc[4].x += vx; acc[4].y += vy; break;
                case 5: acc[5].x += vx; acc[5].y += vy; break;
                case 6: acc[6].x += vx; acc[6].y += vy; break;
                case 7: acc[7].x += vx; acc[7].y += vy; break;
            }
        }
    }
    #pragma unroll
    for (int r = 0; r < N_RELS; ++r) {
        unsigned int u = (unsigned int)f2b(acc[r].x) | ((unsigned int)f2b(acc[r].y) << 16);
        *(unsigned int*)&agg[((size_t)(r * PADN + node)) * 128 + lane * 2] = u;
    }
}

// ---- gemm2: out[n][o] = relu(sum_{r,k} agg[r][n][k] * w[r][k][o] + bias[o])
//      tile 64 nodes x 128 o; Bs-only LDS (16 KB, XOR-swizzled chunks);
//      A-fragments direct from fragment-layout wt2 (L2-hot). ----
__global__ __launch_bounds__(256) void gemm2_kernel(const char* __restrict__ agg,
                                                    const char* __restrict__ wt2,
                                                    const float* __restrict__ bias,
                                                    float* __restrict__ out) {
    __shared__ char Bs[64 * 256];                     // 64 rows x 16 chunks x 16 B
    const int n0 = blockIdx.x * 64;
    const int tid = threadIdx.x;
    const int wave = tid >> 6, lane = tid & 63;
    const int m16 = lane & 15, quad = lane >> 4;
    const int wo = wave & 1;      // o half (64)
    const int wn = wave >> 1;     // node half (32)

    f32x4 acc[4][2];
    #pragma unroll
    for (int og = 0; og < 4; ++og)
        #pragma unroll
        for (int ng = 0; ng < 2; ++ng) acc[og][ng] = (f32x4){0.f, 0.f, 0.f, 0.f};

    const char* aBase = wt2 + wo * 4 * 4096 + m16 * 16;

    for (int r = 0; r < N_RELS; ++r) {
        const char* agr = agg + ((size_t)(r * PADN + n0)) * 256;
        __syncthreads();                               // Bs reuse guard
        #pragma unroll
        for (int i = 0; i < 4; ++i) {
            int s = i * 256 + tid;                     // 1024 chunk-slots
            int row = s >> 4, cs = s & 15;
            uint4 v = *(const uint4*)(agr + row * 256 + cs * 16);        // linear, coalesced
            *(uint4*)&Bs[row * 256 + ((cs ^ (row & 15)) << 4)] = v;      // swizzled store
        }
        __syncthreads();
        const char* ar = aBase + r * 32768;
        #pragma unroll
        for (int kk = 0; kk < 4; ++kk) {
            int c = kk * 4 + quad;
            bf16x8 a[4], b[2];
            #pragma unroll
            for (int og = 0; og < 4; ++og)
                a[og] = *(const bf16x8*)(ar + og * 4096 + c * 256);
            #pragma unroll
            for (int ng = 0; ng < 2; ++ng)
                b[ng] = *(const bf16x8*)&Bs[(wn * 32 + ng * 16 + m16) * 256 + ((c ^ m16) << 4)];
            #pragma unroll
            for (int og = 0; og < 4; ++og)
                #pragma unroll
                for (int ng = 0; ng < 2; ++ng)
                    acc[og][ng] = __builtin_amdgcn_mfma_f32_16x16x32_bf16(a[og], b[ng], acc[og][ng], 0, 0, 0);
        }
    }

    // C/D: col(m16)=node, row(quad*4+reg)=o; fuse bias+relu
    #pragma unroll
    for (int og = 0; og < 4; ++og) {
        int ob = wo * 64 + og * 16 + quad * 4;
        float4 b4 = *(const float4*)&bias[ob];
        #pragma unroll
        for (int ng = 0; ng < 2; ++ng) {
            int n = n0 + wn * 32 + ng * 16 + m16;
            if (n < N_NODES) {
                float4 v;
                v.x = fmaxf(acc[og][ng][0] + b4.x, 0.f);
                v.y = fmaxf(acc[og][ng][1] + b4.y, 0.f);
                v.z = fmaxf(acc[og][ng][2] + b4.z, 0.f);
                v.w = fmaxf(acc[og][ng][3] + b4.w, 0.f);
                *(float4*)&out[(size_t)n * 128 + ob] = v;
            }
        }
    }
}

extern "C" void kernel_launch(void* const* d_in, const int* in_sizes, int n_in,
                              void* d_out, int out_size, void* d_ws, size_t ws_size,
                              hipStream_t stream) {
    const float* h    = (const float*)d_in[0];
    const float* en   = (const float*)d_in[1];
    const int*   et   = (const int*)d_in[2];
    const int*   src  = (const int*)d_in[3];
    const int*   dst  = (const int*)d_in[4];
    const float* w    = (const float*)d_in[5];
    const float* bias = (const float*)d_in[6];
    float* out = (float*)d_out;

    char* ws = (char*)d_ws;
    unsigned short* hb  = (unsigned short*)(ws);                 //  12,800,000 B
    unsigned short* wt2 = (unsigned short*)(ws + 12800000);      //     262,144 B
    unsigned short* agg = (unsigned short*)(ws + 13062144);      // 102,498,304 B (8 * PADN * 256)
    char* sbase = ws + 115560448;
    int*  counts    = (int*)(sbase);
    int*  partial   = (int*)(sbase + 200704);
    int*  bsum      = (int*)(sbase + 401408);
    int*  row_start = (int*)(sbase + 402432);                    // 50001 ints
    int*  cursor    = (int*)(sbase + 603136);
    int2* meta      = (int2*)(sbase + 803840);                   // 6,400,000 B

    (void)hipMemsetAsync(counts, 0, N_NODES * sizeof(int), stream);
    hipLaunchKernelGGL(cvt_h_kernel, dim3(6250), dim3(256), 0, stream, h, hb);
    hipLaunchKernelGGL(cvt_w_kernel, dim3(512), dim3(256), 0, stream, w, wt2);
    hipLaunchKernelGGL(hist_kernel, dim3(N_EDGES / 256), dim3(256), 0, stream, dst, counts);
    hipLaunchKernelGGL(scan1_kernel, dim3(NB_SCAN), dim3(256), 0, stream, counts, partial, bsum);
    hipLaunchKernelGGL(scan2_kernel, dim3(1), dim3(256), 0, stream, bsum);
    hipLaunchKernelGGL(scan3_kernel, dim3(NB_SCAN), dim3(256), 0, stream, partial, bsum, row_start, cursor);
    hipLaunchKernelGGL(scatter_kernel, dim3(N_EDGES / 256), dim3(256), 0, stream, src, dst, et, en, cursor, meta);
    hipLaunchKernelGGL(agg_kernel, dim3(12500), dim3(256), 0, stream, (const char*)hb, meta, row_start, agg);
    hipLaunchKernelGGL(gemm2_kernel, dim3(782), dim3(256), 0, stream, (const char*)agg, (const char*)wt2, bias, out);
}

// Round 7
// 274.574 us; speedup vs baseline: 1.0681x; 1.0681x over previous
//
#include <hip/hip_runtime.h>
#include <hip/hip_bf16.h>

#define N_NODES 50000
#define PADN    50048        // 782 * 64
#define N_EDGES 800000
#define N_RELS  8
#define NKEYS   400000       // nodes * rels
#define NTOT    400384       // 1564 * 256
#define NB1     1564         // NTOT / 256

typedef __attribute__((ext_vector_type(8))) short bf16x8;
typedef __attribute__((ext_vector_type(4))) float f32x4;

typedef const __attribute__((address_space(1))) unsigned int* gptr_t;
typedef __attribute__((address_space(3))) unsigned int* lptr_t;

__device__ __forceinline__ unsigned short f2b(float f) {
    unsigned int u = __float_as_uint(f);
    u += 0x7fffu + ((u >> 16) & 1u);
    return (unsigned short)(u >> 16);
}

// ---- prep: cvt_h (blocks 0..6249) | cvt_w->frag layout (6250..6761) | hist2 (6762..9886) ----
__global__ void prep_kernel(const float* __restrict__ h, unsigned short* __restrict__ hb,
                            const float* __restrict__ w, unsigned short* __restrict__ wt2,
                            const int* __restrict__ dst, const int* __restrict__ et,
                            int* __restrict__ counts2) {
    int b = blockIdx.x;
    if (b < 6250) {
        int i = b * 256 + threadIdx.x;               // 1,600,000 float4 chunks
        float4 v = ((const float4*)h)[i];
        ushort4 o;
        o.x = f2b(v.x); o.y = f2b(v.y); o.z = f2b(v.z); o.w = f2b(v.w);
        ((ushort4*)hb)[i] = o;
    } else if (b < 6762) {
        int idx = (b - 6250) * 256 + threadIdx.x;    // 131072 = 8*128*128
        int r = idx >> 14;
        int k = (idx >> 7) & 127;
        int o = idx & 127;
        // wt2[r][o>>4][k>>3][o&15][k&7]
        int off = (r << 14) + ((o >> 4) << 11) + ((k >> 3) << 7) + ((o & 15) << 3) + (k & 7);
        wt2[off] = f2b(w[idx]);
    } else {
        int e = (b - 6762) * 256 + threadIdx.x;      // 800000
        atomicAdd(&counts2[dst[e] * 8 + et[e]], 1);
    }
}

// ---- scan phase 1: per-block exclusive scan over NTOT keys ----
__global__ void scan1_kernel(const int* __restrict__ counts, int* __restrict__ partial,
                             int* __restrict__ bsum) {
    __shared__ int tmp[256];
    int i = blockIdx.x * 256 + threadIdx.x;          // grid exact: NB1
    int v = counts[i];
    tmp[threadIdx.x] = v;
    __syncthreads();
    #pragma unroll
    for (int off = 1; off < 256; off <<= 1) {
        int t = (threadIdx.x >= off) ? tmp[threadIdx.x - off] : 0;
        __syncthreads();
        tmp[threadIdx.x] += t;
        __syncthreads();
    }
    partial[i] = tmp[threadIdx.x] - v;               // exclusive
    if (threadIdx.x == 255) bsum[blockIdx.x] = tmp[255];
}

// ---- scan phase 2: exclusive scan of NB1 block sums (single block, chunked) ----
__global__ void scan2_kernel(int* __restrict__ bsum) {
    __shared__ int tmp[256];
    int run = 0;
    for (int c = 0; c < NB1; c += 256) {
        int i = c + threadIdx.x;
        int v = (i < NB1) ? bsum[i] : 0;
        tmp[threadIdx.x] = v;
        __syncthreads();
        #pragma unroll
        for (int off = 1; off < 256; off <<= 1) {
            int t = (threadIdx.x >= off) ? tmp[threadIdx.x - off] : 0;
            __syncthreads();
            tmp[threadIdx.x] += t;
            __syncthreads();
        }
        if (i < NB1) bsum[i] = run + tmp[threadIdx.x] - v;
        int tot = tmp[255];
        __syncthreads();
        run += tot;
    }
}

// ---- scan phase 3: add block offsets; init row_start2 + cursor2 ----
__global__ void scan3_kernel(const int* __restrict__ partial, const int* __restrict__ bsum,
                             int* __restrict__ row_start2, int* __restrict__ cursor2) {
    int i = blockIdx.x * 256 + threadIdx.x;          // grid exact: NB1
    int rs = partial[i] + bsum[i >> 8];
    if (i <= NKEYS) row_start2[i] = rs;              // row_start2[NKEYS] == N_EDGES
    if (i < NKEYS) cursor2[i] = rs;
}

// ---- scatter into (dst,rel)-sorted order; meta.x = hb row byte offset ----
__global__ void scatter_kernel(const int* __restrict__ src, const int* __restrict__ dst,
                               const int* __restrict__ et, const float* __restrict__ en,
                               int* __restrict__ cursor2, int2* __restrict__ meta) {
    int e = blockIdx.x * 256 + threadIdx.x;          // grid exact: 3125
    int key = dst[e] * 8 + et[e];
    int pos = atomicAdd(&cursor2[key], 1);
    meta[pos] = make_int2(src[e] << 8, __float_as_int(en[e]));
}

// ---- aggregate: one wave per dst node; compile-time rel segments, fp32 acc;
//      writes agg[r][node][256B] bf16 with XOR-chunk swizzle baked in ----
__global__ __launch_bounds__(256) void agg_kernel(const char* __restrict__ hb,
                                                  const int2* __restrict__ meta,
                                                  const int* __restrict__ row_start2,
                                                  char* __restrict__ agg) {
    int node = blockIdx.x * 4 + (threadIdx.x >> 6);  // 12500 * 4 = 50000
    int lane = threadIdx.x & 63;
    int rs[9];
    #pragma unroll
    for (int r = 0; r < 9; ++r) rs[r] = row_start2[node * 8 + r];

    float2 acc[N_RELS];
    #pragma unroll
    for (int r = 0; r < N_RELS; ++r) acc[r] = make_float2(0.f, 0.f);

    for (int base = rs[0]; base < rs[8]; base += 64) {
        int hi = rs[8]; if (hi > base + 64) hi = base + 64;
        int2 m = make_int2(0, 0);
        if (base + lane < rs[8]) m = meta[base + lane];
        #pragma unroll
        for (int r = 0; r < N_RELS; ++r) {
            int ks = rs[r] > base ? rs[r] : base;
            int ke = rs[r + 1] < hi ? rs[r + 1] : hi;
            for (int k = ks; k < ke; ++k) {
                int off = __shfl(m.x, k - base);
                float w = __uint_as_float(__shfl(m.y, k - base));
                unsigned int v = *(const unsigned int*)(hb + off + lane * 4);
                acc[r].x += __uint_as_float(v << 16) * w;
                acc[r].y += __uint_as_float(v & 0xffff0000u) * w;
            }
        }
    }
    // swizzled write: chunk cs = lane>>2 -> position (cs ^ (node&15))
    int sw = (((lane >> 2) ^ (node & 15)) << 4) + (lane & 3) * 4;
    #pragma unroll
    for (int r = 0; r < N_RELS; ++r) {
        unsigned int u = (unsigned int)f2b(acc[r].x) | ((unsigned int)f2b(acc[r].y) << 16);
        *(unsigned int*)(agg + ((size_t)(r * PADN + node)) * 256 + sw) = u;
    }
}

// ---- gemm2: out[n][o] = relu(sum_{r,k} agg[r][n][k] * w[r][k][o] + bias[o])
//      64-node x 128-o tile; Ws(32KB)+Bs(16KB) staged via global_load_lds;
//      acc carried across all 8 rels; fused bias+relu epilogue ----
__global__ __launch_bounds__(256) void gemm2_kernel(const char* __restrict__ agg,
                                                    const char* __restrict__ wt2,
                                                    const float* __restrict__ bias,
                                                    float* __restrict__ out) {
    __shared__ char Ws[32768];   // wt2[r] plane, fragment layout
    __shared__ char Bs[16384];   // 64 agg rows, source-swizzled
    const int n0 = blockIdx.x * 64;
    const int tid = threadIdx.x;
    const int wave = tid >> 6, lane = tid & 63;
    const int m16 = lane & 15, quad = lane >> 4;

    f32x4 acc[8];
    #pragma unroll
    for (int og = 0; og < 8; ++og) acc[og] = (f32x4){0.f, 0.f, 0.f, 0.f};

    for (int r = 0; r < N_RELS; ++r) {
        __syncthreads();                              // prior compute done before overwrite
        const char* wsrc = wt2 + ((size_t)r << 15);
        const char* bsrc = agg + ((size_t)(r * PADN + n0)) * 256;
        #pragma unroll
        for (int j = 0; j < 8; ++j) {
            int off = j * 4096 + wave * 1024 + lane * 16;
            __builtin_amdgcn_global_load_lds((gptr_t)(wsrc + off), (lptr_t)(Ws + j * 4096 + wave * 1024), 16, 0, 0);
        }
        #pragma unroll
        for (int j = 0; j < 4; ++j) {
            int off = j * 4096 + wave * 1024 + lane * 16;
            __builtin_amdgcn_global_load_lds((gptr_t)(bsrc + off), (lptr_t)(Bs + j * 4096 + wave * 1024), 16, 0, 0);
        }
        __syncthreads();                              // drains vmcnt -> data visible
        #pragma unroll
        for (int kk = 0; kk < 4; ++kk) {
            int c = kk * 4 + quad;
            bf16x8 b = *(const bf16x8*)(Bs + (wave * 16 + m16) * 256 + ((c ^ m16) << 4));
            #pragma unroll
            for (int og = 0; og < 8; ++og) {
                bf16x8 a = *(const bf16x8*)(Ws + og * 4096 + c * 256 + m16 * 16);
                acc[og] = __builtin_amdgcn_mfma_f32_16x16x32_bf16(a, b, acc[og], 0, 0, 0);
            }
        }
    }

    // C/D: col(m16)=node-in-stripe, row(quad*4+reg)=o-in-og
    int n = n0 + wave * 16 + m16;
    if (n < N_NODES) {
        #pragma unroll
        for (int og = 0; og < 8; ++og) {
            int o = og * 16 + quad * 4;
            float4 b4 = *(const float4*)&bias[o];
            float4 v;
            v.x = fmaxf(acc[og][0] + b4.x, 0.f);
            v.y = fmaxf(acc[og][1] + b4.y, 0.f);
            v.z = fmaxf(acc[og][2] + b4.z, 0.f);
            v.w = fmaxf(acc[og][3] + b4.w, 0.f);
            *(float4*)&out[(size_t)n * 128 + o] = v;
        }
    }
}

extern "C" void kernel_launch(void* const* d_in, const int* in_sizes, int n_in,
                              void* d_out, int out_size, void* d_ws, size_t ws_size,
                              hipStream_t stream) {
    const float* h    = (const float*)d_in[0];
    const float* en   = (const float*)d_in[1];
    const int*   et   = (const int*)d_in[2];
    const int*   src  = (const int*)d_in[3];
    const int*   dst  = (const int*)d_in[4];
    const float* w    = (const float*)d_in[5];
    const float* bias = (const float*)d_in[6];
    float* out = (float*)d_out;

    char* ws = (char*)d_ws;
    unsigned short* hb  = (unsigned short*)(ws);                 //  12,800,000 B
    unsigned short* wt2 = (unsigned short*)(ws + 12800000);      //     262,144 B
    char*           agg = ws + 13062144;                         // 102,498,304 B (8 * PADN * 256)
    char* sbase = ws + 115560448;
    int*  counts2    = (int*)(sbase);                            // 1,601,536 B (NTOT) — reused as cursor2
    int*  partial2   = (int*)(sbase + 1601536);                  // 1,601,536 B
    int*  bsum       = (int*)(sbase + 3203072);                  //     6,400 B
    int*  row_start2 = (int*)(sbase + 3209472);                  // 1,600,004 B (NKEYS+1)
    int2* meta       = (int2*)(sbase + 4809728);                 // 6,400,000 B   (total ~126.8 MB)

    int* cursor2 = counts2;   // counts2 dead after scan1 — reuse

    (void)hipMemsetAsync(counts2, 0, NTOT * sizeof(int), stream);
    hipLaunchKernelGGL(prep_kernel, dim3(9887), dim3(256), 0, stream, h, hb, w, wt2, dst, et, counts2);
    hipLaunchKernelGGL(scan1_kernel, dim3(NB1), dim3(256), 0, stream, counts2, partial2, bsum);
    hipLaunchKernelGGL(scan2_kernel, dim3(1), dim3(256), 0, stream, bsum);
    hipLaunchKernelGGL(scan3_kernel, dim3(NB1), dim3(256), 0, stream, partial2, bsum, row_start2, cursor2);
    hipLaunchKernelGGL(scatter_kernel, dim3(N_EDGES / 256), dim3(256), 0, stream, src, dst, et, en, cursor2, meta);
    hipLaunchKernelGGL(agg_kernel, dim3(12500), dim3(256), 0, stream, (const char*)hb, meta, row_start2, agg);
    hipLaunchKernelGGL(gemm2_kernel, dim3(782), dim3(256), 0, stream, (const char*)agg, (const char*)wt2, bias, out);
}